// Round 3
// baseline (339.038 us; speedup 1.0000x reference)
//
#include <hip/hip_runtime.h>
#include <hip/hip_bf16.h>

// out[256, 100000] = (inputs[256,256] @ features[100000,256]^T) / 0.07
//
// Barrier-free design: each block stages one bf16 M-half of A (128x256 =
// 64 KB, XOR-swizzled) into LDS once, then its 16 waves run fully
// independent task loops (one 16-row m-subtile x 16-col n-subtile each,
// K=256 unrolled). No __syncthreads after staging -> no vmcnt(0) drains;
// loads/stores of all 32 resident waves/CU overlap freely.
// N = 100000 = 6250 * 16 exactly -> no tail predication anywhere.

typedef __attribute__((ext_vector_type(8))) __bf16 bf16x8;   // 4 VGPRs
typedef __attribute__((ext_vector_type(4))) float  floatx4;  // MFMA acc
typedef __attribute__((ext_vector_type(4))) unsigned int uint4v;

#define NB    100000
#define KD    256
#define NSUB  6250     // 16-wide n-subtiles (exact)
#define NGRP  512      // concurrent n-groups
#define GRIDB 512

union FragCast { uint4v u; bf16x8 f; };

__device__ __forceinline__ unsigned pk(float a, float b) {
  // v_cvt_pk_bf16_f32 (RNE)
  __hip_bfloat162 h = __float22bfloat162_rn(float2{a, b});
  union { __hip_bfloat162 h2; unsigned u; } c; c.h2 = h; return c.u;
}

__global__ __launch_bounds__(1024, 8)
void sct_gemm(const float* __restrict__ inputs,
              const float* __restrict__ features,
              float* __restrict__ out) {
  // A-half as bf16, row stride 128 dwords, dword-offset XOR-swizzled by
  // (row&7)*16 so stride-512B reads are ~2-way (free) instead of 16-way.
  __shared__ unsigned ldsA[128 * 128];   // 65536 B

  const int tid  = threadIdx.x;
  const int b    = blockIdx.x;
  const int h    = b & 1;          // which M-half this block owns
  const int wv   = tid >> 6;
  const int lane = tid & 63;
  const int quad = lane >> 4;
  const int l16  = lane & 15;
  const float scale = 1.0f / 0.07f;

  // ---- stage A-half once: f32 -> bf16 (scale folded) -> swizzled LDS ----
  // 128 rows x 32 chunks(8 f32) = 4096 chunks, 4 per thread, coalesced.
  #pragma unroll
  for (int i = 0; i < 4; ++i) {
    const int c  = i * 1024 + tid;
    const int r  = c >> 5;
    const int ck = c & 31;
    const float4* p = (const float4*)(inputs + (size_t)(h * 128 + r) * KD + ck * 8);
    const float4 a0 = p[0], a1 = p[1];
    uint4v w;
    w.x = pk(a0.x * scale, a0.y * scale);
    w.y = pk(a0.z * scale, a0.w * scale);
    w.z = pk(a1.x * scale, a1.y * scale);
    w.w = pk(a1.z * scale, a1.w * scale);
    *(uint4v*)&ldsA[r * 128 + ((ck * 4) ^ ((r & 7) * 16))] = w;
  }
  __syncthreads();   // the ONLY barrier

  // ---- per-wave identity ----
  const int mb = wv & 7;                       // m-subtile within half (16 rows)
  const int g  = ((b >> 1) << 1) + (wv >> 3);  // n-group in [0, 512)

  // A-fragment LDS address (task-invariant): row = mb*16+l16,
  // dword off = quad*4 + ((t*16) ^ ((l16&7)*16))
  const unsigned aBase = (unsigned)((mb * 16 + l16) * 128 + quad * 4);
  const unsigned aSwz  = (unsigned)((l16 & 7) * 16);

  // output pointer: row mrow+r, col n0+l16
  const int mrow = h * 128 + mb * 16 + quad * 4;
  float* outp = out + (size_t)mrow * NB + l16;

  const int ntasks = (NSUB - g + NGRP - 1) / NGRP;   // 12 or 13
  const float* featp = features + (size_t)(g * 16 + l16) * KD;

  for (int it = 0; it < ntasks; ++it) {
    floatx4 acc = {0.f, 0.f, 0.f, 0.f};

    #pragma unroll
    for (int t = 0; t < 8; ++t) {
      // B: feat[n=n0+l16][k = t*32 + quad*8 .. +7] -- one addr reg,
      // immediate offsets (t*128 + quad*32 (+16) bytes, all < 4096).
      const float4* pB = (const float4*)(featp + t * 32 + quad * 8);
      const float4 b0 = pB[0], b1 = pB[1];
      FragCast bf;
      bf.u.x = pk(b0.x, b0.y); bf.u.y = pk(b0.z, b0.w);
      bf.u.z = pk(b1.x, b1.y); bf.u.w = pk(b1.z, b1.w);

      FragCast af;
      af.u = *(const uint4v*)&ldsA[aBase + (((unsigned)(t * 16)) ^ aSwz)];

      acc = __builtin_amdgcn_mfma_f32_16x16x32_bf16(af.f, bf.f, acc, 0, 0, 0);
    }

    // store 4 rows x 1 col per lane (64B segments along N, no predication)
    const int n0 = (g + it * NGRP) * 16;
    float* o = outp + n0;
    #pragma unroll
    for (int r = 0; r < 4; ++r)
      o[(size_t)r * NB] = acc[r];

    featp += (size_t)NGRP * 16 * KD;   // advance 8192 feature rows
  }
}

extern "C" void kernel_launch(void* const* d_in, const int* in_sizes, int n_in,
                              void* d_out, int out_size, void* d_ws, size_t ws_size,
                              hipStream_t stream) {
  const float* inputs   = (const float*)d_in[0];  // [256,256] f32
  // d_in[1] = indexes (unused), d_in[3] = momentum (unused)
  const float* features = (const float*)d_in[2];  // [100000,256] f32
  float* out = (float*)d_out;                     // [256,100000] f32

  sct_gemm<<<GRIDB, 1024, 0, stream>>>(inputs, features, out);
}

// Round 4
// 222.065 us; speedup vs baseline: 1.5268x; 1.5268x over previous
//
#include <hip/hip_runtime.h>
#include <hip/hip_bf16.h>

// out[256, 100000] = (inputs[256,256] @ features[100000,256]^T) / 0.07
//
// One-shot grid: 3126 blocks x 512 threads; block = (m-half, 64-wide n-tile).
// All global loads coalesced (consecutive lanes -> consecutive addresses).
// Small per-wave state (afrag 32 + acc 16 VGPRs) + __launch_bounds__(512,8)
// -> VGPR <= 64 -> 4 blocks/CU co-resident (32 waves/CU): inter-block TLP
// hides staging latency and barrier drains without software pipelining.
// m-half pairs are dispatch-adjacent (b&1) so the 2nd features read of each
// tile hits L2/L3 (measured round 3: 2x logical reads -> only +11% FETCH).

typedef __attribute__((ext_vector_type(8))) __bf16 bf16x8;   // 4 VGPRs
typedef __attribute__((ext_vector_type(4))) float  floatx4;  // MFMA acc
typedef __attribute__((ext_vector_type(4))) unsigned int uint4v;

#define NB 100000
#define KD 256
#define BN 64
#define NT 1563            // ceil(NB/BN)
#define LDS_STRIDE 132     // dwords/row: 128 data + 4 pad (16-way -> 8-way spans)

union FragCast { uint4v u; bf16x8 f; };

__device__ __forceinline__ unsigned pk(float a, float b) {
  // v_cvt_pk_bf16_f32 (RNE)
  __hip_bfloat162 h = __float22bfloat162_rn(float2{a, b});
  union { __hip_bfloat162 h2; unsigned u; } c; c.h2 = h; return c.u;
}

__global__ __launch_bounds__(512, 8)
void sct_gemm(const float* __restrict__ inputs,
              const float* __restrict__ features,
              float* __restrict__ out) {
  __shared__ unsigned ldsB[BN * LDS_STRIDE];   // 33792 B bf16 B-tile

  const int tid = threadIdx.x;
  const int b   = blockIdx.x;
  const int mh  = b & 1;            // m-half (pairs dispatch-adjacent)
  const int n0  = (b >> 1) * BN;

  const int wv   = tid >> 6;        // 0..7 -> m-subtile within half
  const int lane = tid & 63;
  const int quad = lane >> 4;
  const int l16  = lane & 15;

  // ---- stage B tile [BN x KD] f32 -> bf16 -> LDS, fully coalesced ----
  // chunk c = i*512 + tid: row r = c>>5, 8-float chunk ck = c&31.
  #pragma unroll
  for (int i = 0; i < 4; ++i) {
    const int c  = i * 512 + tid;
    const int r  = c >> 5;
    const int ck = c & 31;
    const int n  = n0 + r;
    float4 f0 = make_float4(0.f, 0.f, 0.f, 0.f), f1 = f0;
    if (n < NB) {
      const float4* p = (const float4*)(features + (size_t)n * KD + ck * 8);
      f0 = p[0]; f1 = p[1];
    }
    uint4v w;
    w.x = pk(f0.x, f0.y); w.y = pk(f0.z, f0.w);
    w.z = pk(f1.x, f1.y); w.w = pk(f1.z, f1.w);
    *(uint4v*)&ldsB[r * LDS_STRIDE + ck * 4] = w;
  }

  // ---- A fragments: wave's 16 rows of inputs (L2-hot), scale folded ----
  const float scale = 1.0f / 0.07f;
  bf16x8 afrag[8];                  // 32 VGPRs
  {
    const float* arow = inputs + (size_t)(mh * 128 + wv * 16 + l16) * KD + quad * 8;
    #pragma unroll
    for (int t = 0; t < 8; ++t) {
      const float4* p = (const float4*)(arow + t * 32);
      const float4 a0 = p[0], a1 = p[1];
      FragCast fc;
      fc.u.x = pk(a0.x * scale, a0.y * scale);
      fc.u.y = pk(a0.z * scale, a0.w * scale);
      fc.u.z = pk(a1.x * scale, a1.y * scale);
      fc.u.w = pk(a1.z * scale, a1.w * scale);
      afrag[t] = fc.f;
    }
  }

  __syncthreads();

  // ---- MFMA: 1 m-subtile x 4 n-subtiles, K=256 in 8 steps ----
  floatx4 acc[4];
  #pragma unroll
  for (int nt = 0; nt < 4; ++nt) acc[nt] = floatx4{0.f, 0.f, 0.f, 0.f};

  #pragma unroll
  for (int t = 0; t < 8; ++t) {
    #pragma unroll
    for (int nt = 0; nt < 4; ++nt) {
      FragCast fc;
      fc.u = *(const uint4v*)&ldsB[(nt * 16 + l16) * LDS_STRIDE + t * 16 + quad * 4];
      acc[nt] = __builtin_amdgcn_mfma_f32_16x16x32_bf16(afrag[t], fc.f, acc[nt], 0, 0, 0);
    }
  }

  // ---- store: D col = l16 (64B segments along N), row = quad*4 + r ----
  const int mbase = mh * 128 + wv * 16 + quad * 4;
  #pragma unroll
  for (int nt = 0; nt < 4; ++nt) {
    const int n = n0 + nt * 16 + l16;
    if (n < NB) {
      #pragma unroll
      for (int r = 0; r < 4; ++r)
        out[(size_t)(mbase + r) * NB + n] = acc[nt][r];
    }
  }
}

extern "C" void kernel_launch(void* const* d_in, const int* in_sizes, int n_in,
                              void* d_out, int out_size, void* d_ws, size_t ws_size,
                              hipStream_t stream) {
  const float* inputs   = (const float*)d_in[0];  // [256,256] f32
  // d_in[1] = indexes (unused), d_in[3] = momentum (unused)
  const float* features = (const float*)d_in[2];  // [100000,256] f32
  float* out = (float*)d_out;                     // [256,100000] f32

  sct_gemm<<<2 * NT, 512, 0, stream>>>(inputs, features, out);
}